// Round 5
// baseline (650.639 us; speedup 1.0000x reference)
//
#include <hip/hip_runtime.h>

#define HW   1024
#define DHW  16384

typedef __attribute__((ext_vector_type(8))) short short8;
typedef __attribute__((ext_vector_type(4))) float f32x4;

static __device__ __forceinline__ ushort f2bf(float f) {
  unsigned u = __float_as_uint(f);
  unsigned r = (u + 0x7fffu + ((u >> 16) & 1u)) >> 16;
  return (ushort)r;
}
static __device__ __forceinline__ float bf2f(ushort u) {
  return __uint_as_float(((unsigned)u) << 16);
}
static __device__ __forceinline__ void async_copy16(const ushort* g, ushort* l) {
  __builtin_amdgcn_global_load_lds(
      (const __attribute__((address_space(1))) unsigned int*)g,
      (__attribute__((address_space(3))) unsigned int*)l, 16, 0, 0);
}

// ---------------------------------------------------------------------------
// k/q 1x1x1 conv
// ---------------------------------------------------------------------------
__global__ __launch_bounds__(256) void kq_kernel(
    const float* __restrict__ x, const float* __restrict__ wk,
    const float* __restrict__ bk, const float* __restrict__ wq,
    const float* __restrict__ bq, float* __restrict__ k, float* __restrict__ q) {
  __shared__ float wks[16 * 128];
  __shared__ float wqs[16 * 128];
  int tid = threadIdx.x;
  for (int i = tid; i < 2048; i += 256) { wks[i] = wk[i]; wqs[i] = wq[i]; }
  __syncthreads();
  int b = blockIdx.y;
  int p = blockIdx.x * 256 + tid;
  float ak[16], aq[16];
#pragma unroll
  for (int o = 0; o < 16; ++o) { ak[o] = 0.f; aq[o] = 0.f; }
  const float* xb = x + (size_t)b * 128 * DHW + p;
  for (int c = 0; c < 128; ++c) {
    float xv = xb[(size_t)c * DHW];
#pragma unroll
    for (int o = 0; o < 16; ++o) {
      ak[o] += wks[o * 128 + c] * xv;
      aq[o] += wqs[o * 128 + c] * xv;
    }
  }
#pragma unroll
  for (int o = 0; o < 16; ++o) {
    k[((size_t)b * 16 + o) * DHW + p] = ak[o] + bk[o];
    q[((size_t)b * 16 + o) * DHW + p] = aq[o] + bq[o];
  }
}

// ---------------------------------------------------------------------------
// weight prep: wt2[kd][chunk(16)][tap(9)][o(128)][8c] <- wv[o][c][kd,kh,kw]
// ---------------------------------------------------------------------------
__global__ __launch_bounds__(256) void wprep_kernel(
    const float* __restrict__ wv, ushort* __restrict__ wt,
    ushort* __restrict__ zbuf) {
  if (blockIdx.x == 0 && threadIdx.x < 512) zbuf[threadIdx.x] = 0;
  int i = blockIdx.x * 256 + threadIdx.x;
  if (i >= 27 * 128 * 128) return;
  int c8 = i & 7;
  int t = i >> 3;
  int o = t & 127; t >>= 7;
  int tap = t % 9; t /= 9;
  int chunk = t & 15;
  int kd = t >> 4;
  wt[i] = f2bf(wv[(size_t)(o * 128 + chunk * 8 + c8) * 27 + kd * 9 + tap]);
}

// ---------------------------------------------------------------------------
// x prep: xt2[b][z][chunk(16)][hw(1024)][8c] <- x[b][c][z][h][w] fp32
// ---------------------------------------------------------------------------
__global__ __launch_bounds__(256) void xprep_kernel(
    const float* __restrict__ x, ushort* __restrict__ xt) {
  __shared__ __align__(16) ushort tile[32 * 136];
  int tid = threadIdx.x;
  int bz = blockIdx.y;
  int b = bz >> 4, z = bz & 15;
  int p0 = blockIdx.x * 32;
  for (int i = tid; i < 4096; i += 256) {
    int c = i >> 5, p = i & 31;
    tile[p * 136 + c] = f2bf(x[((size_t)(b * 128 + c) * 16 + z) * 1024 + p0 + p]);
  }
  __syncthreads();
  for (int i = tid; i < 512; i += 256) {
    int chunk = i >> 5, p = i & 31;
    uint4 val = *(const uint4*)&tile[p * 136 + chunk * 8];
    *(uint4*)&xt[(((size_t)bz * 16 + chunk) * 1024 + p0 + p) * 8] = val;
  }
}

// ---------------------------------------------------------------------------
// v 3x3x3 conv as implicit-GEMM bf16 MFMA; staging via global_load_lds DMA.
// ---------------------------------------------------------------------------
__global__ __launch_bounds__(256, 2) void vconv_mfma_kernel(
    const ushort* __restrict__ xt, const ushort* __restrict__ wt,
    const float* __restrict__ bv, const ushort* __restrict__ zbuf,
    ushort* __restrict__ v) {
  __shared__ __align__(16) ushort xs[1536 * 8];
  __shared__ __align__(16) ushort wsm[2304 * 8];
  int tid = threadIdx.x;
  int wave = tid >> 6;
  int ml = tid & 15;
  int quad = (tid >> 4) & 3;
  int bz = blockIdx.z;
  int b = bz >> 4, z = bz & 15;
  int o0 = blockIdx.y * 64;
  int h0 = blockIdx.x * 8;

  f32x4 acc[4][4];
#pragma unroll
  for (int s = 0; s < 4; ++s)
#pragma unroll
    for (int t = 0; t < 4; ++t) acc[s][t] = (f32x4){0.f, 0.f, 0.f, 0.f};

  int cb0[4];
#pragma unroll
  for (int t = 0; t < 4; ++t)
    cb0[t] = (wave * 2 + (t >> 1)) * 34 + (t & 1) * 16 + ml;

  int xoff[6]; bool okx[6];
#pragma unroll
  for (int it = 0; it < 6; ++it) {
    int i = it * 256 + tid;
    int cu = i / 340;
    int cell = i - cu * 340;
    int hr = cell / 34;
    int wc = cell - hr * 34;
    int h = h0 + hr - 1, ww = wc - 1;
    okx[it] = (i < 1360) && ((unsigned)h < 32u) && ((unsigned)ww < 32u);
    xoff[it] = cu * 1024 + h * 32 + ww;
  }
  int woff[9];
#pragma unroll
  for (int it = 0; it < 9; ++it) {
    int i = it * 256 + tid;
    int cu = i / 576;
    int r = i - cu * 576;
    int tap = r >> 6, ol = r & 63;
    woff[it] = (cu * 9 + tap) * 128 + o0 + ol;
  }

  const int KH[9] = {0, 0, 0, 1, 1, 1, 2, 2, 2};
  const int KW[9] = {0, 1, 2, 0, 1, 2, 0, 1, 2};

  for (int kd = 0; kd < 3; ++kd) {
    int zd = z + kd - 1;
    bool zok = (zd >= 0 && zd < 16);
    int zdc = zok ? zd : 0;
    const ushort* xbase = xt + (size_t)(b * 16 + zdc) * 16 * 1024 * 8;
    for (int cb = 0; cb < 4; ++cb) {
      const ushort* xsb = xbase + (size_t)cb * 4 * 1024 * 8;
      const ushort* wsb = wt + (size_t)(kd * 16 + cb * 4) * 9 * 128 * 8;
#pragma unroll
      for (int it = 0; it < 6; ++it) {
        const ushort* g = (zok && okx[it]) ? xsb + (size_t)xoff[it] * 8 : zbuf;
        async_copy16(g, &xs[(it * 256 + tid) * 8]);
      }
#pragma unroll
      for (int it = 0; it < 9; ++it)
        async_copy16(wsb + (size_t)woff[it] * 8, &wsm[(it * 256 + tid) * 8]);
      __syncthreads();
#pragma unroll
      for (int tap = 0; tap < 9; ++tap) {
        const int kh = KH[tap], kw = KW[tap];
        short8 af[4], bfr[4];
#pragma unroll
        for (int s = 0; s < 4; ++s)
          af[s] = *(const short8*)&wsm[(quad * 576 + tap * 64 + s * 16 + ml) * 8];
#pragma unroll
        for (int t = 0; t < 4; ++t) {
          int cell = cb0[t] + kh * 34 + kw;
          bfr[t] = *(const short8*)&xs[(quad * 340 + cell) * 8];
        }
#pragma unroll
        for (int s = 0; s < 4; ++s)
#pragma unroll
          for (int t = 0; t < 4; ++t)
            acc[s][t] = __builtin_amdgcn_mfma_f32_16x16x32_bf16(af[s], bfr[t], acc[s][t], 0, 0, 0);
      }
      __syncthreads();
    }
  }
#pragma unroll
  for (int s = 0; s < 4; ++s) {
    int o = o0 + s * 16 + quad * 4;
#pragma unroll
    for (int t = 0; t < 4; ++t) {
      int pl = wave * 64 + t * 16 + ml;
      ushort* dst = &v[((size_t)(b * 128 + o) * 16 + z) * 1024 + h0 * 32 + pl];
#pragma unroll
      for (int r = 0; r < 4; ++r)
        dst[(size_t)r * 16384] = f2bf(acc[s][t][r] + bv[o + r]);
    }
  }
}

// ---------------------------------------------------------------------------
// A_p spatial attention softmax; output bf16
// ---------------------------------------------------------------------------
__global__ __launch_bounds__(256) void ap_kernel(
    const float* __restrict__ k, const float* __restrict__ q,
    ushort* __restrict__ A_p) {
  __shared__ float ks[256 * 16];
  __shared__ float wred[16][4];
  int tid = threadIdx.x;
  int b = blockIdx.y;
  int s0 = blockIdx.x * 16;
  for (int i = tid; i < 4096; i += 256) {
    int f = i >> 4, sl = i & 15;
    ks[i] = k[((size_t)b * 256 + f) * HW + s0 + sl];
  }
  __syncthreads();
  float acc[16][4];
#pragma unroll
  for (int sl = 0; sl < 16; ++sl)
#pragma unroll
    for (int jt = 0; jt < 4; ++jt) acc[sl][jt] = 0.f;
  const float* qb = q + (size_t)b * 256 * HW;
  for (int f = 0; f < 256; ++f) {
    float qv0 = qb[f * HW + tid];
    float qv1 = qb[f * HW + tid + 256];
    float qv2 = qb[f * HW + tid + 512];
    float qv3 = qb[f * HW + tid + 768];
#pragma unroll
    for (int sl = 0; sl < 16; ++sl) {
      float kv = ks[f * 16 + sl];
      acc[sl][0] += kv * qv0;
      acc[sl][1] += kv * qv1;
      acc[sl][2] += kv * qv2;
      acc[sl][3] += kv * qv3;
    }
  }
  int lane = tid & 63, wid = tid >> 6;
#pragma unroll
  for (int sl = 0; sl < 16; ++sl) {
    float m = fmaxf(fmaxf(acc[sl][0], acc[sl][1]), fmaxf(acc[sl][2], acc[sl][3]));
    for (int off = 32; off >= 1; off >>= 1) m = fmaxf(m, __shfl_xor(m, off));
    if (lane == 0) wred[sl][wid] = m;
  }
  __syncthreads();
  float rsum[16];
#pragma unroll
  for (int sl = 0; sl < 16; ++sl) {
    float rm = fmaxf(fmaxf(wred[sl][0], wred[sl][1]), fmaxf(wred[sl][2], wred[sl][3]));
    float s = 0.f;
#pragma unroll
    for (int jt = 0; jt < 4; ++jt) {
      acc[sl][jt] = __expf(acc[sl][jt] - rm);
      s += acc[sl][jt];
    }
    for (int off = 32; off >= 1; off >>= 1) s += __shfl_xor(s, off);
    rsum[sl] = s;
  }
  __syncthreads();
#pragma unroll
  for (int sl = 0; sl < 16; ++sl)
    if (lane == 0) wred[sl][wid] = rsum[sl];
  __syncthreads();
#pragma unroll
  for (int sl = 0; sl < 16; ++sl) {
    float s = wred[sl][0] + wred[sl][1] + wred[sl][2] + wred[sl][3];
    float inv = 1.f / s;
    ushort* row = A_p + ((size_t)b * 1024 + s0 + sl) * 1024;
    row[tid]       = f2bf(acc[sl][0] * inv);
    row[tid + 256] = f2bf(acc[sl][1] * inv);
    row[tid + 512] = f2bf(acc[sl][2] * inv);
    row[tid + 768] = f2bf(acc[sl][3] * inv);
  }
}

// ---------------------------------------------------------------------------
// A_d depth attention softmax
// ---------------------------------------------------------------------------
__global__ __launch_bounds__(256) void ad_kernel(
    const float* __restrict__ k, const float* __restrict__ q,
    float* __restrict__ A_d) {
  int tid = threadIdx.x;
  int b = blockIdx.x >> 4;
  int dj = blockIdx.x & 15;
  float acc[16];
#pragma unroll
  for (int e = 0; e < 16; ++e) acc[e] = 0.f;
  const float* kb = k + (size_t)b * 256 * HW;
  const float* qb = q + (size_t)b * 256 * HW;
  for (int f = tid; f < 16384; f += 256) {
    int oc = f >> 10, hw = f & 1023;
    float kv = kb[(oc * 16 + dj) * HW + hw];
#pragma unroll
    for (int e = 0; e < 16; ++e)
      acc[e] += kv * qb[(oc * 16 + e) * HW + hw];
  }
  __shared__ float sred[16][4];
  __shared__ float arow[16];
  __shared__ float prow[16];
  int lane = tid & 63, wid = tid >> 6;
#pragma unroll
  for (int e = 0; e < 16; ++e) {
    float s = acc[e];
    for (int off = 32; off >= 1; off >>= 1) s += __shfl_xor(s, off);
    if (lane == 0) sred[e][wid] = s;
  }
  __syncthreads();
  if (tid < 16) arow[tid] = sred[tid][0] + sred[tid][1] + sred[tid][2] + sred[tid][3];
  __syncthreads();
  if (tid < 16) {
    float m = arow[0];
    for (int e = 1; e < 16; ++e) m = fmaxf(m, arow[e]);
    prow[tid] = __expf(arow[tid] - m);
  }
  __syncthreads();
  if (tid < 16) {
    float s = 0.f;
    for (int e = 0; e < 16; ++e) s += prow[e];
    A_d[(size_t)b * 256 + dj * 16 + tid] = prow[tid] / s;
  }
}

// ---------------------------------------------------------------------------
// combine: Patt = vf @ A_p^T via bf16 MFMA, operands streamed DIRECTLY from
// global to VGPR fragments (K-contiguous 16B loads) — no LDS, no barriers in
// the K-loop. Fused Datt + residual epilogue uses LDS afterwards.
// ---------------------------------------------------------------------------
__global__ __launch_bounds__(256, 3) void combine_mfma_kernel(
    const ushort* __restrict__ vb, const ushort* __restrict__ apb,
    const float* __restrict__ A_d, const float* __restrict__ x,
    const float* __restrict__ gamma, float* __restrict__ out) {
  __shared__ __align__(16) ushort smem[16384];  // epilogue v subtile (32 KB)
  __shared__ float Ads[256];
  int tid = threadIdx.x;
  int wave = tid >> 6, lane = tid & 63;
  int ml = lane & 15, quad = lane >> 4;
  int wm = wave >> 1, wj = wave & 1;
  int b = blockIdx.z;
  int m0 = blockIdx.y * 128;
  int j0 = blockIdx.x * 128;
  Ads[tid] = A_d[b * 256 + tid];

  f32x4 acc[4][4];
#pragma unroll
  for (int s = 0; s < 4; ++s)
#pragma unroll
    for (int t = 0; t < 4; ++t) acc[s][t] = (f32x4){0.f, 0.f, 0.f, 0.f};

  // lane-private fragment base pointers (K-contiguous rows)
  const ushort* va = vb + ((size_t)b * 2048 + m0 + wm * 64 + ml) * 1024 + quad * 8;
  const ushort* pa = apb + ((size_t)b * 1024 + j0 + wj * 64 + ml) * 1024 + quad * 8;

#pragma unroll 2
  for (int kk = 0; kk < 1024; kk += 64) {
    short8 af[4][2], bf[4][2];
#pragma unroll
    for (int s = 0; s < 4; ++s)
#pragma unroll
      for (int ks = 0; ks < 2; ++ks)
        af[s][ks] = *(const short8*)&va[(size_t)s * 16 * 1024 + kk + ks * 32];
#pragma unroll
    for (int t = 0; t < 4; ++t)
#pragma unroll
      for (int ks = 0; ks < 2; ++ks)
        bf[t][ks] = *(const short8*)&pa[(size_t)t * 16 * 1024 + kk + ks * 32];
#pragma unroll
    for (int ks = 0; ks < 2; ++ks)
#pragma unroll
      for (int s = 0; s < 4; ++s)
#pragma unroll
        for (int t = 0; t < 4; ++t)
          acc[s][t] = __builtin_amdgcn_mfma_f32_16x16x32_bf16(af[s][ks], bf[t][ks], acc[s][t], 0, 0, 0);
  }

  // ---- epilogue: stage v[m0:+128][j0:+128] bf16 into smem
  for (int i = tid; i < 2048; i += 256) {
    int row = i >> 4, jc = i & 15;
    uint4 val = *(const uint4*)&vb[((size_t)b * 2048 + m0 + row) * 1024 + j0 + jc * 8];
    *(uint4*)&smem[row * 128 + jc * 8] = val;
  }
  __syncthreads();

  float g = gamma[0];
#pragma unroll
  for (int s = 0; s < 4; ++s) {
#pragma unroll
    for (int t = 0; t < 4; ++t) {
      int jrel = wj * 64 + t * 16 + ml;
      float dat[4] = {0.f, 0.f, 0.f, 0.f};
#pragma unroll
      for (int d = 0; d < 16; ++d) {
        float vv = bf2f(smem[(wm * 64 + s * 16 + d) * 128 + jrel]);
#pragma unroll
        for (int r = 0; r < 4; ++r)
          dat[r] += Ads[(quad * 4 + r) * 16 + d] * vv;
      }
#pragma unroll
      for (int r = 0; r < 4; ++r) {
        int m = m0 + wm * 64 + s * 16 + quad * 4 + r;
        int j = j0 + jrel;
        size_t idx = ((size_t)b * 2048 + m) * 1024 + j;
        out[idx] = g * (acc[s][t][r] + dat[r]) + x[idx];
      }
    }
  }
}

// ---------------------------------------------------------------------------
extern "C" void kernel_launch(void* const* d_in, const int* in_sizes, int n_in,
                              void* d_out, int out_size, void* d_ws, size_t ws_size,
                              hipStream_t stream) {
  const float* x     = (const float*)d_in[0];
  const float* gamma = (const float*)d_in[1];
  const float* w_k   = (const float*)d_in[2];
  const float* b_k   = (const float*)d_in[3];
  const float* w_q   = (const float*)d_in[4];
  const float* b_q   = (const float*)d_in[5];
  const float* w_v   = (const float*)d_in[6];
  const float* b_v   = (const float*)d_in[7];
  float* out = (float*)d_out;

  float* k    = (float*)d_ws;            // 2,097,152 f32
  float* q    = k + 2097152;             // 2,097,152 f32
  float* A_d  = q + 2097152;             // 2,048 f32
  ushort* vbf = (ushort*)(A_d + 2048);   // 16,777,216 bf16
  ushort* apb = vbf + 16777216;          // 8,388,608 bf16
  ushort* wt  = apb + 8388608;           // 442,368 bf16
  ushort* zbuf = wt + 442368;            // 512 bf16 zeros
  ushort* xt  = zbuf + 512;              // 16,777,216 bf16

  wprep_kernel<<<dim3(1728), 256, 0, stream>>>(w_v, wt, zbuf);
  xprep_kernel<<<dim3(32, 128), 256, 0, stream>>>(x, xt);
  kq_kernel<<<dim3(64, 8), 256, 0, stream>>>(x, w_k, b_k, w_q, b_q, k, q);
  vconv_mfma_kernel<<<dim3(4, 2, 128), 256, 0, stream>>>(xt, wt, b_v, zbuf, vbf);
  ap_kernel<<<dim3(64, 8), 256, 0, stream>>>(k, q, apb);
  ad_kernel<<<dim3(128), 256, 0, stream>>>(k, q, A_d);
  combine_mfma_kernel<<<dim3(8, 16, 8), 256, 0, stream>>>(vbf, apb, A_d, x, gamma, out);
}

// Round 6
// 483.402 us; speedup vs baseline: 1.3460x; 1.3460x over previous
//
#include <hip/hip_runtime.h>

#define HW   1024
#define DHW  16384

typedef __attribute__((ext_vector_type(8))) short short8;
typedef __attribute__((ext_vector_type(4))) float f32x4;

static __device__ __forceinline__ ushort f2bf(float f) {
  unsigned u = __float_as_uint(f);
  unsigned r = (u + 0x7fffu + ((u >> 16) & 1u)) >> 16;
  return (ushort)r;
}
static __device__ __forceinline__ float bf2f(ushort u) {
  return __uint_as_float(((unsigned)u) << 16);
}
static __device__ __forceinline__ void async_copy16(const ushort* g, ushort* l) {
  __builtin_amdgcn_global_load_lds(
      (const __attribute__((address_space(1))) unsigned int*)g,
      (__attribute__((address_space(3))) unsigned int*)l, 16, 0, 0);
}

// ---------------------------------------------------------------------------
// k/q 1x1x1 conv
// ---------------------------------------------------------------------------
__global__ __launch_bounds__(256) void kq_kernel(
    const float* __restrict__ x, const float* __restrict__ wk,
    const float* __restrict__ bk, const float* __restrict__ wq,
    const float* __restrict__ bq, float* __restrict__ k, float* __restrict__ q) {
  __shared__ float wks[16 * 128];
  __shared__ float wqs[16 * 128];
  int tid = threadIdx.x;
  for (int i = tid; i < 2048; i += 256) { wks[i] = wk[i]; wqs[i] = wq[i]; }
  __syncthreads();
  int b = blockIdx.y;
  int p = blockIdx.x * 256 + tid;
  float ak[16], aq[16];
#pragma unroll
  for (int o = 0; o < 16; ++o) { ak[o] = 0.f; aq[o] = 0.f; }
  const float* xb = x + (size_t)b * 128 * DHW + p;
  for (int c = 0; c < 128; ++c) {
    float xv = xb[(size_t)c * DHW];
#pragma unroll
    for (int o = 0; o < 16; ++o) {
      ak[o] += wks[o * 128 + c] * xv;
      aq[o] += wqs[o * 128 + c] * xv;
    }
  }
#pragma unroll
  for (int o = 0; o < 16; ++o) {
    k[((size_t)b * 16 + o) * DHW + p] = ak[o] + bk[o];
    q[((size_t)b * 16 + o) * DHW + p] = aq[o] + bq[o];
  }
}

// ---------------------------------------------------------------------------
// weight prep: wt2[kd][chunk(16)][tap(9)][o(128)][8c] <- wv[o][c][kd,kh,kw]
// ---------------------------------------------------------------------------
__global__ __launch_bounds__(256) void wprep_kernel(
    const float* __restrict__ wv, ushort* __restrict__ wt,
    ushort* __restrict__ zbuf) {
  if (blockIdx.x == 0 && threadIdx.x < 512) zbuf[threadIdx.x] = 0;
  int i = blockIdx.x * 256 + threadIdx.x;
  if (i >= 27 * 128 * 128) return;
  int c8 = i & 7;
  int t = i >> 3;
  int o = t & 127; t >>= 7;
  int tap = t % 9; t /= 9;
  int chunk = t & 15;
  int kd = t >> 4;
  wt[i] = f2bf(wv[(size_t)(o * 128 + chunk * 8 + c8) * 27 + kd * 9 + tap]);
}

// ---------------------------------------------------------------------------
// x prep: xt2[b][z][chunk(16)][hw(1024)][8c] <- x[b][c][z][h][w] fp32
// ---------------------------------------------------------------------------
__global__ __launch_bounds__(256) void xprep_kernel(
    const float* __restrict__ x, ushort* __restrict__ xt) {
  __shared__ __align__(16) ushort tile[32 * 136];
  int tid = threadIdx.x;
  int bz = blockIdx.y;
  int b = bz >> 4, z = bz & 15;
  int p0 = blockIdx.x * 32;
  for (int i = tid; i < 4096; i += 256) {
    int c = i >> 5, p = i & 31;
    tile[p * 136 + c] = f2bf(x[((size_t)(b * 128 + c) * 16 + z) * 1024 + p0 + p]);
  }
  __syncthreads();
  for (int i = tid; i < 512; i += 256) {
    int chunk = i >> 5, p = i & 31;
    uint4 val = *(const uint4*)&tile[p * 136 + chunk * 8];
    *(uint4*)&xt[(((size_t)bz * 16 + chunk) * 1024 + p0 + p) * 8] = val;
  }
}

// ---------------------------------------------------------------------------
// v 3x3x3 conv as implicit-GEMM bf16 MFMA; staging via global_load_lds DMA.
// Grid (128 bz, 4 h, 2 o): all 8 tiles of one (b,z) land on XCD bz%8 so the
// shared x-slab stays hot in that XCD's L2.
// ---------------------------------------------------------------------------
__global__ __launch_bounds__(256, 2) void vconv_mfma_kernel(
    const ushort* __restrict__ xt, const ushort* __restrict__ wt,
    const float* __restrict__ bv, const ushort* __restrict__ zbuf,
    ushort* __restrict__ v) {
  __shared__ __align__(16) ushort xs[1536 * 8];
  __shared__ __align__(16) ushort wsm[2304 * 8];
  int tid = threadIdx.x;
  int wave = tid >> 6;
  int ml = tid & 15;
  int quad = (tid >> 4) & 3;
  int bz = blockIdx.x;
  int b = bz >> 4, z = bz & 15;
  int h0 = blockIdx.y * 8;
  int o0 = blockIdx.z * 64;

  f32x4 acc[4][4];
#pragma unroll
  for (int s = 0; s < 4; ++s)
#pragma unroll
    for (int t = 0; t < 4; ++t) acc[s][t] = (f32x4){0.f, 0.f, 0.f, 0.f};

  int cb0[4];
#pragma unroll
  for (int t = 0; t < 4; ++t)
    cb0[t] = (wave * 2 + (t >> 1)) * 34 + (t & 1) * 16 + ml;

  int xoff[6]; bool okx[6];
#pragma unroll
  for (int it = 0; it < 6; ++it) {
    int i = it * 256 + tid;
    int cu = i / 340;
    int cell = i - cu * 340;
    int hr = cell / 34;
    int wc = cell - hr * 34;
    int h = h0 + hr - 1, ww = wc - 1;
    okx[it] = (i < 1360) && ((unsigned)h < 32u) && ((unsigned)ww < 32u);
    xoff[it] = cu * 1024 + h * 32 + ww;
  }
  int woff[9];
#pragma unroll
  for (int it = 0; it < 9; ++it) {
    int i = it * 256 + tid;
    int cu = i / 576;
    int r = i - cu * 576;
    int tap = r >> 6, ol = r & 63;
    woff[it] = (cu * 9 + tap) * 128 + o0 + ol;
  }

  const int KH[9] = {0, 0, 0, 1, 1, 1, 2, 2, 2};
  const int KW[9] = {0, 1, 2, 0, 1, 2, 0, 1, 2};

  for (int kd = 0; kd < 3; ++kd) {
    int zd = z + kd - 1;
    bool zok = (zd >= 0 && zd < 16);
    int zdc = zok ? zd : 0;
    const ushort* xbase = xt + (size_t)(b * 16 + zdc) * 16 * 1024 * 8;
    for (int cb = 0; cb < 4; ++cb) {
      const ushort* xsb = xbase + (size_t)cb * 4 * 1024 * 8;
      const ushort* wsb = wt + (size_t)(kd * 16 + cb * 4) * 9 * 128 * 8;
#pragma unroll
      for (int it = 0; it < 6; ++it) {
        const ushort* g = (zok && okx[it]) ? xsb + (size_t)xoff[it] * 8 : zbuf;
        async_copy16(g, &xs[(it * 256 + tid) * 8]);
      }
#pragma unroll
      for (int it = 0; it < 9; ++it)
        async_copy16(wsb + (size_t)woff[it] * 8, &wsm[(it * 256 + tid) * 8]);
      __syncthreads();
#pragma unroll
      for (int tap = 0; tap < 9; ++tap) {
        const int kh = KH[tap], kw = KW[tap];
        short8 af[4], bfr[4];
#pragma unroll
        for (int s = 0; s < 4; ++s)
          af[s] = *(const short8*)&wsm[(quad * 576 + tap * 64 + s * 16 + ml) * 8];
#pragma unroll
        for (int t = 0; t < 4; ++t) {
          int cell = cb0[t] + kh * 34 + kw;
          bfr[t] = *(const short8*)&xs[(quad * 340 + cell) * 8];
        }
#pragma unroll
        for (int s = 0; s < 4; ++s)
#pragma unroll
          for (int t = 0; t < 4; ++t)
            acc[s][t] = __builtin_amdgcn_mfma_f32_16x16x32_bf16(af[s], bfr[t], acc[s][t], 0, 0, 0);
      }
      __syncthreads();
    }
  }
#pragma unroll
  for (int s = 0; s < 4; ++s) {
    int o = o0 + s * 16 + quad * 4;
#pragma unroll
    for (int t = 0; t < 4; ++t) {
      int pl = wave * 64 + t * 16 + ml;
      ushort* dst = &v[((size_t)(b * 128 + o) * 16 + z) * 1024 + h0 * 32 + pl];
#pragma unroll
      for (int r = 0; r < 4; ++r)
        dst[(size_t)r * 16384] = f2bf(acc[s][t][r] + bv[o + r]);
    }
  }
}

// ---------------------------------------------------------------------------
// A_p spatial attention softmax; output bf16
// ---------------------------------------------------------------------------
__global__ __launch_bounds__(256) void ap_kernel(
    const float* __restrict__ k, const float* __restrict__ q,
    ushort* __restrict__ A_p) {
  __shared__ float ks[256 * 16];
  __shared__ float wred[16][4];
  int tid = threadIdx.x;
  int b = blockIdx.y;
  int s0 = blockIdx.x * 16;
  for (int i = tid; i < 4096; i += 256) {
    int f = i >> 4, sl = i & 15;
    ks[i] = k[((size_t)b * 256 + f) * HW + s0 + sl];
  }
  __syncthreads();
  float acc[16][4];
#pragma unroll
  for (int sl = 0; sl < 16; ++sl)
#pragma unroll
    for (int jt = 0; jt < 4; ++jt) acc[sl][jt] = 0.f;
  const float* qb = q + (size_t)b * 256 * HW;
  for (int f = 0; f < 256; ++f) {
    float qv0 = qb[f * HW + tid];
    float qv1 = qb[f * HW + tid + 256];
    float qv2 = qb[f * HW + tid + 512];
    float qv3 = qb[f * HW + tid + 768];
#pragma unroll
    for (int sl = 0; sl < 16; ++sl) {
      float kv = ks[f * 16 + sl];
      acc[sl][0] += kv * qv0;
      acc[sl][1] += kv * qv1;
      acc[sl][2] += kv * qv2;
      acc[sl][3] += kv * qv3;
    }
  }
  int lane = tid & 63, wid = tid >> 6;
#pragma unroll
  for (int sl = 0; sl < 16; ++sl) {
    float m = fmaxf(fmaxf(acc[sl][0], acc[sl][1]), fmaxf(acc[sl][2], acc[sl][3]));
    for (int off = 32; off >= 1; off >>= 1) m = fmaxf(m, __shfl_xor(m, off));
    if (lane == 0) wred[sl][wid] = m;
  }
  __syncthreads();
  float rsum[16];
#pragma unroll
  for (int sl = 0; sl < 16; ++sl) {
    float rm = fmaxf(fmaxf(wred[sl][0], wred[sl][1]), fmaxf(wred[sl][2], wred[sl][3]));
    float s = 0.f;
#pragma unroll
    for (int jt = 0; jt < 4; ++jt) {
      acc[sl][jt] = __expf(acc[sl][jt] - rm);
      s += acc[sl][jt];
    }
    for (int off = 32; off >= 1; off >>= 1) s += __shfl_xor(s, off);
    rsum[sl] = s;
  }
  __syncthreads();
#pragma unroll
  for (int sl = 0; sl < 16; ++sl)
    if (lane == 0) wred[sl][wid] = rsum[sl];
  __syncthreads();
#pragma unroll
  for (int sl = 0; sl < 16; ++sl) {
    float s = wred[sl][0] + wred[sl][1] + wred[sl][2] + wred[sl][3];
    float inv = 1.f / s;
    ushort* row = A_p + ((size_t)b * 1024 + s0 + sl) * 1024;
    row[tid]       = f2bf(acc[sl][0] * inv);
    row[tid + 256] = f2bf(acc[sl][1] * inv);
    row[tid + 512] = f2bf(acc[sl][2] * inv);
    row[tid + 768] = f2bf(acc[sl][3] * inv);
  }
}

// ---------------------------------------------------------------------------
// A_d depth attention softmax
// ---------------------------------------------------------------------------
__global__ __launch_bounds__(256) void ad_kernel(
    const float* __restrict__ k, const float* __restrict__ q,
    float* __restrict__ A_d) {
  int tid = threadIdx.x;
  int b = blockIdx.x >> 4;
  int dj = blockIdx.x & 15;
  float acc[16];
#pragma unroll
  for (int e = 0; e < 16; ++e) acc[e] = 0.f;
  const float* kb = k + (size_t)b * 256 * HW;
  const float* qb = q + (size_t)b * 256 * HW;
  for (int f = tid; f < 16384; f += 256) {
    int oc = f >> 10, hw = f & 1023;
    float kv = kb[(oc * 16 + dj) * HW + hw];
#pragma unroll
    for (int e = 0; e < 16; ++e)
      acc[e] += kv * qb[(oc * 16 + e) * HW + hw];
  }
  __shared__ float sred[16][4];
  __shared__ float arow[16];
  __shared__ float prow[16];
  int lane = tid & 63, wid = tid >> 6;
#pragma unroll
  for (int e = 0; e < 16; ++e) {
    float s = acc[e];
    for (int off = 32; off >= 1; off >>= 1) s += __shfl_xor(s, off);
    if (lane == 0) sred[e][wid] = s;
  }
  __syncthreads();
  if (tid < 16) arow[tid] = sred[tid][0] + sred[tid][1] + sred[tid][2] + sred[tid][3];
  __syncthreads();
  if (tid < 16) {
    float m = arow[0];
    for (int e = 1; e < 16; ++e) m = fmaxf(m, arow[e]);
    prow[tid] = __expf(arow[tid] - m);
  }
  __syncthreads();
  if (tid < 16) {
    float s = 0.f;
    for (int e = 0; e < 16; ++e) s += prow[e];
    A_d[(size_t)b * 256 + dj * 16 + tid] = prow[tid] / s;
  }
}

// ---------------------------------------------------------------------------
// combine: Patt = vf @ A_p^T via bf16 MFMA (128x128, BK=64, global_load_lds,
// XOR chunk swizzle) + fused Datt + residual epilogue.
// Grid (8 b, 128 tiles): all tiles of batch b land on XCD b%8 -> A_p_b (2MB)
// and the active v row-block stay hot in that XCD's L2.
// ---------------------------------------------------------------------------
__global__ __launch_bounds__(256, 2) void combine_mfma_kernel(
    const ushort* __restrict__ vb, const ushort* __restrict__ apb,
    const float* __restrict__ A_d, const float* __restrict__ x,
    const float* __restrict__ gamma, float* __restrict__ out) {
  __shared__ __align__(16) ushort smem[17408];  // K-loop: As/Bs; epilogue: v tile (stride 136)
  __shared__ float Ads[256];
  ushort* As = smem;
  ushort* Bs = smem + 8192;
  int tid = threadIdx.x;
  int wave = tid >> 6, lane = tid & 63;
  int ml = lane & 15, quad = lane >> 4;
  int wm = wave >> 1, wj = wave & 1;
  int b = blockIdx.x;                    // XCD = wg_linear % 8 = b
  int tile = blockIdx.y;
  int m0 = (tile >> 3) * 128;            // m outer
  int j0 = (tile & 7) * 128;             // j inner (A_p block reused back-to-back)
  Ads[tid] = A_d[b * 256 + tid];

  f32x4 acc[4][4];
#pragma unroll
  for (int s = 0; s < 4; ++s)
#pragma unroll
    for (int t = 0; t < 4; ++t) acc[s][t] = (f32x4){0.f, 0.f, 0.f, 0.f};

  const ushort* va = vb + ((size_t)b * 2048 + m0) * 1024;
  const ushort* pa = apb + ((size_t)b * 1024 + j0) * 1024;

  int slot[4], srow[4], skc[4];
#pragma unroll
  for (int n = 0; n < 4; ++n) {
    slot[n] = wave * 256 + n * 64 + lane;
    srow[n] = slot[n] >> 3;
    skc[n] = (slot[n] & 7) ^ (srow[n] & 7);
  }

  for (int kk = 0; kk < 1024; kk += 64) {
#pragma unroll
    for (int n = 0; n < 4; ++n) {
      const ushort* gA = va + (size_t)srow[n] * 1024 + kk + skc[n] * 8;
      const ushort* gB = pa + (size_t)srow[n] * 1024 + kk + skc[n] * 8;
      async_copy16(gA, &As[(wave * 256 + n * 64) * 8]);
      async_copy16(gB, &Bs[(wave * 256 + n * 64) * 8]);
    }
    __syncthreads();
#pragma unroll
    for (int ks = 0; ks < 2; ++ks) {
      short8 af[4], bf[4];
#pragma unroll
      for (int s = 0; s < 4; ++s) {
        int row = wm * 64 + s * 16 + ml;
        int c = ks * 4 + quad;
        af[s] = *(const short8*)&As[(row * 8 + (c ^ (row & 7))) * 8];
      }
#pragma unroll
      for (int t = 0; t < 4; ++t) {
        int row = wj * 64 + t * 16 + ml;
        int c = ks * 4 + quad;
        bf[t] = *(const short8*)&Bs[(row * 8 + (c ^ (row & 7))) * 8];
      }
#pragma unroll
      for (int s = 0; s < 4; ++s)
#pragma unroll
        for (int t = 0; t < 4; ++t)
          acc[s][t] = __builtin_amdgcn_mfma_f32_16x16x32_bf16(af[s], bf[t], acc[s][t], 0, 0, 0);
    }
    __syncthreads();
  }

  // ---- epilogue: stage v[m0:+128][j0:+128] bf16 into smem (stride 136)
  for (int i = tid; i < 2048; i += 256) {
    int row = i >> 4, jc = i & 15;
    uint4 val = *(const uint4*)&vb[((size_t)b * 2048 + m0 + row) * 1024 + j0 + jc * 8];
    *(uint4*)&smem[row * 136 + jc * 8] = val;
  }
  __syncthreads();

  float g = gamma[0];
#pragma unroll
  for (int s = 0; s < 4; ++s) {
#pragma unroll
    for (int t = 0; t < 4; ++t) {
      int jrel = wj * 64 + t * 16 + ml;
      float dat[4] = {0.f, 0.f, 0.f, 0.f};
#pragma unroll
      for (int d = 0; d < 16; ++d) {
        float vv = bf2f(smem[(wm * 64 + s * 16 + d) * 136 + jrel]);
#pragma unroll
        for (int r = 0; r < 4; ++r)
          dat[r] += Ads[(quad * 4 + r) * 16 + d] * vv;
      }
#pragma unroll
      for (int r = 0; r < 4; ++r) {
        int m = m0 + wm * 64 + s * 16 + quad * 4 + r;
        int j = j0 + jrel;
        size_t idx = ((size_t)b * 2048 + m) * 1024 + j;
        out[idx] = g * (acc[s][t][r] + dat[r]) + x[idx];
      }
    }
  }
}

// ---------------------------------------------------------------------------
extern "C" void kernel_launch(void* const* d_in, const int* in_sizes, int n_in,
                              void* d_out, int out_size, void* d_ws, size_t ws_size,
                              hipStream_t stream) {
  const float* x     = (const float*)d_in[0];
  const float* gamma = (const float*)d_in[1];
  const float* w_k   = (const float*)d_in[2];
  const float* b_k   = (const float*)d_in[3];
  const float* w_q   = (const float*)d_in[4];
  const float* b_q   = (const float*)d_in[5];
  const float* w_v   = (const float*)d_in[6];
  const float* b_v   = (const float*)d_in[7];
  float* out = (float*)d_out;

  float* k    = (float*)d_ws;            // 2,097,152 f32
  float* q    = k + 2097152;             // 2,097,152 f32
  float* A_d  = q + 2097152;             // 2,048 f32
  ushort* vbf = (ushort*)(A_d + 2048);   // 16,777,216 bf16
  ushort* apb = vbf + 16777216;          // 8,388,608 bf16
  ushort* wt  = apb + 8388608;           // 442,368 bf16
  ushort* zbuf = wt + 442368;            // 512 bf16 zeros
  ushort* xt  = zbuf + 512;              // 16,777,216 bf16

  wprep_kernel<<<dim3(1728), 256, 0, stream>>>(w_v, wt, zbuf);
  xprep_kernel<<<dim3(32, 128), 256, 0, stream>>>(x, xt);
  kq_kernel<<<dim3(64, 8), 256, 0, stream>>>(x, w_k, b_k, w_q, b_q, k, q);
  vconv_mfma_kernel<<<dim3(128, 4, 2), 256, 0, stream>>>(xt, wt, b_v, zbuf, vbf);
  ap_kernel<<<dim3(64, 8), 256, 0, stream>>>(k, q, apb);
  ad_kernel<<<dim3(128), 256, 0, stream>>>(k, q, A_d);
  combine_mfma_kernel<<<dim3(8, 128), 256, 0, stream>>>(vbf, apb, A_d, x, gamma, out);
}